// Round 5
// baseline (342.419 us; speedup 1.0000x reference)
//
#include <hip/hip_runtime.h>

// MPS encoder, segmented-chain, pairwise folding, register-resident chain.
// R5: LDS-op diet. Evidence: R0-R4 all ~140us regardless of schedule; per-CU
// LDS-pipe op count (~90 ops/wave/interval at ~6cy) matches the measured
// ~10K cy/interval => LDS-op-throughput bound. Changes:
//  - M stored in FRAGMENT-ORDER slots: product reads = 1x ds_read_b128 (MA
//    pa0+pa1) + 2x ds_read_b64 (MB pb0,pb1) per bi  (was 32 split b32 reads).
//  - slot index bit-permutation sigma + XOR(batch) into bank bits: build
//    writes <=4-way conflicts, ALL write addressing folded into imm offsets.
//  - XS deleted: x B-fragments loaded per-lane direct from global (L1-shared)
//    and converted in-register; builds are wave-independent.
// Math identical to R3/R4 (verified): same MFMAs, same cvt_frag, same scaling.
// Scaling: core8 = fp8(16*core); frags hold 16*true values; combine /16 per seg.

#define NSITES 128
#define FEATD  64
#define BOND   32
#define OUTD   256
#define BT     16
#define SEGLEN 16
#define NSEG   (NSITES / SEGLEN)   // 8
#define NPAIR  (SEGLEN / 2)        // 8
#define NBT    (2048 / BT)         // 128

#define MAHALF 16384               // MB region offset inside one buffer
#define BUFSZ  32768               // MA 16KB + MB 16KB

typedef __attribute__((ext_vector_type(4))) float float4v;

__device__ __forceinline__ unsigned pk4_fp8(float a, float b, float c, float d) {
    int v = __builtin_amdgcn_cvt_pk_fp8_f32(a, b, 0, false);
    v = __builtin_amdgcn_cvt_pk_fp8_f32(c, d, v, true);
    return (unsigned)v;
}

// D-layout pair (I=0 c0, I=1 c1 of one J-col) -> A/B fragment, x1/16 scale.
__device__ __forceinline__ long cvt_frag(float4v c0, float4v c1,
                                         int idxlo, int idxhi, int selhi) {
    const float s = 0.0625f;
    int d0 = (int)pk4_fp8(c0[0] * s, c0[1] * s, c0[2] * s, c0[3] * s);
    int d1 = (int)pk4_fp8(c1[0] * s, c1[1] * s, c1[2] * s, c1[3] * s);
    int l0 = __builtin_amdgcn_ds_bpermute(idxlo, d0);
    int l1 = __builtin_amdgcn_ds_bpermute(idxlo, d1);
    int h0 = __builtin_amdgcn_ds_bpermute(idxhi, d0);
    int h1 = __builtin_amdgcn_ds_bpermute(idxhi, d1);
    unsigned lo = (unsigned)(selhi ? l1 : l0);
    unsigned hi = (unsigned)(selhi ? h1 : h0);
    return (long)(((unsigned long long)hi << 32) | (unsigned long long)lo);
}

__device__ __forceinline__ void build_mfmas(const long af[16], long bx0, long bx1,
                                            float4v acc[8]) {
#pragma unroll
    for (int i = 0; i < 8; ++i) {
        float4v z = {0.f, 0.f, 0.f, 0.f};
        z = __builtin_amdgcn_mfma_f32_16x16x32_fp8_fp8(af[2 * i + 0], bx0, z, 0, 0, 0);
        acc[i] = __builtin_amdgcn_mfma_f32_16x16x32_fp8_fp8(af[2 * i + 1], bx1, z, 0, 0, 0);
    }
}

// MA slot layout (16B slots, per batch 64 slots = 1KB):
//   logical idx = (d&15)*4 + (r>>3); byte-in-slot = (d>>4)*8 + (r&7)
//   physical slot = sigma(idx) ^ (batch&7 on low3), sigma: low3={i0,i4,i5}
//   build_a folds to: vA + i*128 (derivation in session log; bijective)
__device__ __forceinline__ void packA(const float4v acc[8], unsigned char* buf, int vA) {
#pragma unroll
    for (int i = 0; i < 8; ++i)
        *(unsigned*)&buf[vA + i * 128] =
            pk4_fp8(acc[i][0], acc[i][1], acc[i][2], acc[i][3]);
}

// MB slot layout (8B slots, per batch 128 slots = 1KB):
//   s = ((r&15)*4 + (d>>3))*2 + (r>>4); dword-in-slot = (d&7)>>2
//   physical = sigma2(s) ^ (batch&15 on low4); build_b folds to vB + g*256 + p*128
__device__ __forceinline__ void packB(const float4v acc[8], unsigned char* buf, int vB) {
#pragma unroll
    for (int p = 0; p < 2; ++p)
#pragma unroll
        for (int g = 0; g < 4; ++g)
            *(unsigned*)&buf[vB + g * 256 + p * 128] =
                pk4_fp8(acc[0 + p][g], acc[2 + p][g], acc[4 + p][g], acc[6 + p][g]);
}

__device__ __forceinline__ void xload(const float* xlane, int s, float4 r[4]) {
    const float* p = xlane + (size_t)s * FEATD;
    r[0] = *(const float4*)(p);
    r[1] = *(const float4*)(p + 4);
    r[2] = *(const float4*)(p + 32);
    r[3] = *(const float4*)(p + 36);
}

__device__ __forceinline__ void xcvt(const float4 r[4], long& b0, long& b1) {
    unsigned l0 = pk4_fp8(r[0].x, r[0].y, r[0].z, r[0].w);
    unsigned h0 = pk4_fp8(r[1].x, r[1].y, r[1].z, r[1].w);
    unsigned l1 = pk4_fp8(r[2].x, r[2].y, r[2].z, r[2].w);
    unsigned h1 = pk4_fp8(r[3].x, r[3].y, r[3].z, r[3].w);
    b0 = (long)(((unsigned long long)h0 << 32) | l0);
    b1 = (long)(((unsigned long long)h1 << 32) | l1);
}

// cores [n][d][f][r] fp32 -> core8 [n][c=d*32+r][f] fp8 (x16), LDS transpose.
__global__ __launch_bounds__(256)
void prep_cores8(const float* __restrict__ cores, unsigned char* __restrict__ core8) {
    __shared__ float tile[FEATD][BOND + 4];
    const int nd = blockIdx.x;            // n*32 + d
    const int t  = threadIdx.x;
    const float* src = cores + (size_t)nd * (FEATD * BOND);
    {
        int base = t * 8;
        int f = base >> 5, r0 = base & 31;
        float4 v0 = *(const float4*)(src + base);
        float4 v1 = *(const float4*)(src + base + 4);
        tile[f][r0 + 0] = v0.x; tile[f][r0 + 1] = v0.y;
        tile[f][r0 + 2] = v0.z; tile[f][r0 + 3] = v0.w;
        tile[f][r0 + 4] = v1.x; tile[f][r0 + 5] = v1.y;
        tile[f][r0 + 6] = v1.z; tile[f][r0 + 7] = v1.w;
    }
    __syncthreads();
    const int r = t >> 3, f0 = (t & 7) * 8;
    const float s = 16.0f;
    unsigned lo = pk4_fp8(tile[f0 + 0][r] * s, tile[f0 + 1][r] * s,
                          tile[f0 + 2][r] * s, tile[f0 + 3][r] * s);
    unsigned hi = pk4_fp8(tile[f0 + 4][r] * s, tile[f0 + 5][r] * s,
                          tile[f0 + 6][r] * s, tile[f0 + 7][r] * s);
    uint2 w; w.x = lo; w.y = hi;
    *(uint2*)(core8 + ((size_t)nd * BOND + r) * FEATD + f0) = w;
}

__global__ __launch_bounds__(512, 4)
void mps_seg(const float* __restrict__ x, const unsigned char* __restrict__ core8,
             unsigned char* __restrict__ Pout) {
    __shared__ __align__(16) unsigned char BUF[2][BUFSZ];

    const int t    = threadIdx.x;
    const int wave = t >> 6;
    const int lane = t & 63;
    const int cl   = lane & 15;
    const int q    = lane >> 4;
    const int seg  = blockIdx.x;          // seg == XCD
    const int bt   = blockIdx.y;
    const int b0   = bt * BT;

    // ---------- writer bases (all store addressing via imm offsets) ----------
    const int vA = (cl << 10)
                 + (((((q >> 1) & 1) | ((wave & 3) << 1)) ^ (cl & 7)) << 4)
                 + (((wave >> 2) & 1) << 3) + ((q & 1) << 2);
    const int vB = MAHALF + (cl << 10)
                 + ((((q & 3) | (((wave >> 1) & 3) << 2)) ^ (cl & 15)) << 3)
                 + ((wave & 1) << 2);

    // ---------- reader addresses, per bi (precomputed, loop-invariant) ------
    const int permA = (q & 1) | (((cl >> 2) & 1) << 1) | (((cl >> 3) & 1) << 2)
                    | (((q >> 1) & 1) << 3) | ((cl & 1) << 4) | (((cl >> 1) & 1) << 5);
    const int sB0 = ((cl >> 2) & 3) | ((q & 3) << 2) | ((cl & 3) << 5);
    int aA[2], aB0[2], aB1[2];
#pragma unroll
    for (int bi = 0; bi < 2; ++bi) {
        int bb = wave * 2 + bi;
        aA[bi]  = (bb << 10) + ((permA ^ (bb & 7)) << 4);
        aB0[bi] = MAHALF + (bb << 10) + ((sB0 ^ (bb & 15)) << 3);
        aB1[bi] = MAHALF + (bb << 10) + (((sB0 | 16) ^ (bb & 15)) << 3);
    }

    const int idxlo = (cl + 16 * ((2 * q) & 3)) << 2;
    const int idxhi = (cl + 16 * ((2 * q + 1) & 3)) << 2;
    const int selhi = q >> 1;

    // running product P (= 16*I) as B-fragments
    long ps[2][2];
#pragma unroll
    for (int J = 0; J < 2; ++J) {
        int row = J * 16 + cl;
        int jj  = row - 8 * q;
        long v  = (jj >= 0 && jj < 8) ? (long)(0x58ULL << (8 * jj)) : 0L;
        ps[0][J] = v;
        ps[1][J] = v;
    }

    const int n0 = seg * SEGLEN;
    // x: lane loads its own B-fragment row (batch = b0+cl), feats q*8..
    const float* xlane = x + ((size_t)(b0 + cl) * NSITES + n0) * FEATD + q * 8;
    // core8: per-site base + lane offset; per-load addressing = imm i*1024(+32)
    const unsigned char* cbase = core8 + (size_t)n0 * (1024 * FEATD)
                               + (size_t)(wave * 8192 + cl * 64 + q * 8);
#define AF_LOAD(A, s_) { const unsigned char* p_ = cbase + (size_t)(s_) * 65536; \
    _Pragma("unroll") for (int i_ = 0; i_ < 8; ++i_) { \
        (A)[2*i_+0] = *(const long*)(p_ + i_*1024); \
        (A)[2*i_+1] = *(const long*)(p_ + i_*1024 + 32); } }

    long af[16];
    long bxe0, bxe1, bxo0, bxo1;
    float4 ra[4], rb[4];

    // ---------------- prologue: build pair 0 -> BUF[0] ----------------
    AF_LOAD(af, 0);
    xload(xlane, 0, ra);
    xload(xlane, 1, rb);
    xcvt(ra, bxe0, bxe1);
    xcvt(rb, bxo0, bxo1);
    {
        float4v acc[8];
        build_mfmas(af, bxe0, bxe1, acc);
        AF_LOAD(af, 1);
        packA(acc, BUF[0], vA);
        xload(xlane, 2, ra);                  // pair 1 even
        float4v accb[8];
        build_mfmas(af, bxo0, bxo1, accb);
        AF_LOAD(af, 2);
        packB(accb, BUF[0], vB);
        xload(xlane, 3, rb);                  // pair 1 odd
    }
    __syncthreads();

    // -------- main: interval j = product(j) + build(pair j+1), 1 barrier ----
    for (int j = 0; j < NPAIR - 1; ++j) {
        const unsigned char* bufc = BUF[j & 1];
        unsigned char* bufn = BUF[(j + 1) & 1];

        // convert x staged last interval (loads have had a full interval)
        xcvt(ra, bxe0, bxe1);
        xcvt(rb, bxo0, bxo1);

        // product fragment reads FIRST (consumed at interval end)
        long pa0[2], pa1[2], pb0[2], pb1[2];
#pragma unroll
        for (int bi = 0; bi < 2; ++bi) {
            uint4 v = *(const uint4*)(bufc + aA[bi]);              // ds_read_b128
            pa0[bi] = (long)(((unsigned long long)v.y << 32) | v.x);
            pa1[bi] = (long)(((unsigned long long)v.w << 32) | v.z);
            pb0[bi] = *(const long*)(bufc + aB0[bi]);              // ds_read_b64
            pb1[bi] = *(const long*)(bufc + aB1[bi]);
        }

        // build even site of pair j+1
        {
            float4v acc[8];
            build_mfmas(af, bxe0, bxe1, acc);
            AF_LOAD(af, 2 * j + 3);
            packA(acc, bufn, vA);
        }
        const bool more = (j + 2 < NPAIR);
        xload(xlane, more ? 2 * j + 4 : 0, ra);
        // build odd site of pair j+1
        {
            float4v accb[8];
            build_mfmas(af, bxo0, bxo1, accb);
            AF_LOAD(af, (j + 1 < NPAIR - 1) ? 2 * j + 4 : 0);
            packB(accb, bufn, vB);
        }
        xload(xlane, more ? 2 * j + 5 : 0, rb);

        // product chain for pair j (serial critical path)
        __builtin_amdgcn_s_setprio(1);
#pragma unroll
        for (int bi = 0; bi < 2; ++bi) {
            float4v z00 = {0.f,0.f,0.f,0.f}, z01 = {0.f,0.f,0.f,0.f};
            float4v z10 = {0.f,0.f,0.f,0.f}, z11 = {0.f,0.f,0.f,0.f};
            z00 = __builtin_amdgcn_mfma_f32_16x16x32_fp8_fp8(pa0[bi], pb0[bi], z00, 0, 0, 0);
            z01 = __builtin_amdgcn_mfma_f32_16x16x32_fp8_fp8(pa0[bi], pb1[bi], z01, 0, 0, 0);
            z10 = __builtin_amdgcn_mfma_f32_16x16x32_fp8_fp8(pa1[bi], pb0[bi], z10, 0, 0, 0);
            z11 = __builtin_amdgcn_mfma_f32_16x16x32_fp8_fp8(pa1[bi], pb1[bi], z11, 0, 0, 0);
            long ca0 = cvt_frag(z00, z10, idxlo, idxhi, selhi);
            long ca1 = cvt_frag(z01, z11, idxlo, idxhi, selhi);
            float4v c00 = {0.f,0.f,0.f,0.f}, c01 = {0.f,0.f,0.f,0.f};
            float4v c10 = {0.f,0.f,0.f,0.f}, c11 = {0.f,0.f,0.f,0.f};
            c00 = __builtin_amdgcn_mfma_f32_16x16x32_fp8_fp8(ca0, ps[bi][0], c00, 0, 0, 0);
            c01 = __builtin_amdgcn_mfma_f32_16x16x32_fp8_fp8(ca0, ps[bi][1], c01, 0, 0, 0);
            c10 = __builtin_amdgcn_mfma_f32_16x16x32_fp8_fp8(ca1, ps[bi][0], c10, 0, 0, 0);
            c11 = __builtin_amdgcn_mfma_f32_16x16x32_fp8_fp8(ca1, ps[bi][1], c11, 0, 0, 0);
            ps[bi][0] = cvt_frag(c00, c10, idxlo, idxhi, selhi);
            ps[bi][1] = cvt_frag(c01, c11, idxlo, idxhi, selhi);
        }
        __builtin_amdgcn_s_setprio(0);
        __syncthreads();
    }

    // ---------------- final product (pair NPAIR-1, BUF[1]) ----------------
    {
        const unsigned char* bufc = BUF[(NPAIR - 1) & 1];
#pragma unroll
        for (int bi = 0; bi < 2; ++bi) {
            uint4 v = *(const uint4*)(bufc + aA[bi]);
            long pa0 = (long)(((unsigned long long)v.y << 32) | v.x);
            long pa1 = (long)(((unsigned long long)v.w << 32) | v.z);
            long pb0 = *(const long*)(bufc + aB0[bi]);
            long pb1 = *(const long*)(bufc + aB1[bi]);
            float4v z00 = {0.f,0.f,0.f,0.f}, z01 = {0.f,0.f,0.f,0.f};
            float4v z10 = {0.f,0.f,0.f,0.f}, z11 = {0.f,0.f,0.f,0.f};
            z00 = __builtin_amdgcn_mfma_f32_16x16x32_fp8_fp8(pa0, pb0, z00, 0, 0, 0);
            z01 = __builtin_amdgcn_mfma_f32_16x16x32_fp8_fp8(pa0, pb1, z01, 0, 0, 0);
            z10 = __builtin_amdgcn_mfma_f32_16x16x32_fp8_fp8(pa1, pb0, z10, 0, 0, 0);
            z11 = __builtin_amdgcn_mfma_f32_16x16x32_fp8_fp8(pa1, pb1, z11, 0, 0, 0);
            long ca0 = cvt_frag(z00, z10, idxlo, idxhi, selhi);
            long ca1 = cvt_frag(z01, z11, idxlo, idxhi, selhi);
            float4v c00 = {0.f,0.f,0.f,0.f}, c01 = {0.f,0.f,0.f,0.f};
            float4v c10 = {0.f,0.f,0.f,0.f}, c11 = {0.f,0.f,0.f,0.f};
            c00 = __builtin_amdgcn_mfma_f32_16x16x32_fp8_fp8(ca0, ps[bi][0], c00, 0, 0, 0);
            c01 = __builtin_amdgcn_mfma_f32_16x16x32_fp8_fp8(ca0, ps[bi][1], c01, 0, 0, 0);
            c10 = __builtin_amdgcn_mfma_f32_16x16x32_fp8_fp8(ca1, ps[bi][0], c10, 0, 0, 0);
            c11 = __builtin_amdgcn_mfma_f32_16x16x32_fp8_fp8(ca1, ps[bi][1], c11, 0, 0, 0);
            ps[bi][0] = cvt_frag(c00, c10, idxlo, idxhi, selhi);
            ps[bi][1] = cvt_frag(c01, c11, idxlo, idxhi, selhi);
        }
    }

    // ---------------- dump via BUF[0], coalesced global store ----------------
#pragma unroll
    for (int bi = 0; bi < 2; ++bi) {
        const int bb = wave * 2 + bi;
#pragma unroll
        for (int J = 0; J < 2; ++J)
            *(long*)&BUF[0][bb * 1024 + (J * 16 + cl) * 32 + q * 8] = ps[bi][J];
    }
    __syncthreads();
    {
        const uint4* p = (const uint4*)&BUF[0][t * 32];
        uint4* g = (uint4*)(Pout + ((size_t)seg * 2048 + b0) * 1024 + (size_t)t * 32);
        g[0] = p[0];
        g[1] = p[1];
    }
#undef AF_LOAD
}

__global__ __launch_bounds__(256)
void combine(const unsigned char* __restrict__ Pout, const float* __restrict__ startv,
             const float* __restrict__ endv, const float* __restrict__ fc_w,
             const float* __restrict__ fc_b, float* __restrict__ out) {
    __shared__ __align__(16) unsigned char st[8 * 1024];
    __shared__ float resA[8][33], resB[8][33];
    __shared__ float val[8];
    const int t  = threadIdx.x;
    const int b0 = blockIdx.x * 8;
    const int bb = t >> 5, r = t & 31;

    uint4 ga[NSEG][2];
#pragma unroll
    for (int s = 0; s < NSEG; ++s) {
        const uint4* g = (const uint4*)(Pout + ((size_t)s * 2048 + b0) * 1024 + (size_t)t * 32);
        ga[s][0] = g[0];
        ga[s][1] = g[1];
    }

    resA[bb][r] = startv[r];
    for (int s = 0; s < NSEG; ++s) {
        {
            uint4* p = (uint4*)&st[t * 32];
            p[0] = ga[s][0];
            p[1] = ga[s][1];
        }
        __syncthreads();
        const float* rin = (s & 1) ? &resB[bb][0] : &resA[bb][0];
        float* rout      = (s & 1) ? &resA[bb][0] : &resB[bb][0];
        float acc = 0.f;
#pragma unroll
        for (int d = 0; d < BOND; ++d) {
            int byte = st[bb * 1024 + d * 32 + r];
            acc += rin[d] * __builtin_amdgcn_cvt_f32_fp8(byte, 0);
        }
        rout[r] = acc * 0.0625f;
        __syncthreads();
    }
    float prod = resA[bb][r] * endv[r];
#pragma unroll
    for (int off = 16; off >= 1; off >>= 1) prod += __shfl_down(prod, off, 32);
    if (r == 0) val[bb] = prod;
    __syncthreads();

    const float v = val[t >> 5];
    const int j0 = (t & 31) * 8;
    const int ob = b0 + (t >> 5);
#pragma unroll
    for (int i = 0; i < 2; ++i) {
        int j = j0 + i * 4;
        float4 w4 = *(const float4*)(fc_w + j);
        float4 bbv = *(const float4*)(fc_b + j);
        float4 o;
        o.x = v * w4.x + bbv.x;
        o.y = v * w4.y + bbv.y;
        o.z = v * w4.z + bbv.z;
        o.w = v * w4.w + bbv.w;
        *(float4*)(out + (size_t)ob * OUTD + j) = o;
    }
}

extern "C" void kernel_launch(void* const* d_in, const int* in_sizes, int n_in,
                              void* d_out, int out_size, void* d_ws, size_t ws_size,
                              hipStream_t stream) {
    const float* x      = (const float*)d_in[0];
    const float* cores  = (const float*)d_in[1];
    const float* startv = (const float*)d_in[2];
    const float* endv   = (const float*)d_in[3];
    const float* fc_w   = (const float*)d_in[4];
    const float* fc_b   = (const float*)d_in[5];
    float* out = (float*)d_out;

    unsigned char* core8 = (unsigned char*)d_ws;                       // 8.4 MB
    unsigned char* Pout  = core8 + (size_t)NSITES * 1024 * FEATD;      // 16.8 MB

    prep_cores8<<<NSITES * BOND, 256, 0, stream>>>(cores, core8);
    mps_seg<<<dim3(NSEG, NBT), 512, 0, stream>>>(x, core8, Pout);
    combine<<<2048 / 8, 256, 0, stream>>>(Pout, startv, endv, fc_w, fc_b, out);
}